// Round 5
// baseline (158.092 us; speedup 1.0000x reference)
//
#include <hip/hip_runtime.h>
#include <hip/hip_bf16.h>
#include <math.h>

#define H 256
#define BQ 1024
#define NPOOL 32768
#define MAXN 64
#define NB 512  // fused grid: 2 blocks/CU on 256 CUs -> all co-resident

typedef __attribute__((ext_vector_type(8))) short short8;
typedef __attribute__((ext_vector_type(8))) unsigned short ushort8v;
typedef __attribute__((ext_vector_type(4))) float f32x4;

__device__ __forceinline__ unsigned short f2bf(float f) {
  unsigned int u = __float_as_uint(f);
  unsigned int r = (u + 0x7fffu + ((u >> 16) & 1u)) >> 16;
  return (unsigned short)r;
}
__device__ __forceinline__ float b2f(unsigned short u) {
  return __uint_as_float((unsigned int)u << 16);
}
__device__ __forceinline__ unsigned int cvt_pk_bf16(float a, float b) {
  unsigned int r;
  asm("v_cvt_pk_bf16_f32 %0, %1, %2" : "=v"(r) : "v"(a), "v"(b));
  return r;
}
__device__ __forceinline__ void gload16(const void* g, void* l) {
  __builtin_amdgcn_global_load_lds(
      (const __attribute__((address_space(1))) unsigned int*)g,
      (__attribute__((address_space(3))) unsigned int*)l, 16, 0, 0);
}

// Device-scope grid barrier. bar[2*idx] = arrive counter, bar[2*idx+1] = flag.
// bar region is zeroed by a hipMemsetAsync node before every kernel launch.
__device__ __forceinline__ void grid_barrier(unsigned* bar, int idx) {
  __syncthreads();
  if (threadIdx.x == 0) {
    __threadfence();  // publish this block's global writes (device scope)
    if (atomicAdd(&bar[2 * idx], 1u) == NB - 1) {
      atomicExch(&bar[2 * idx + 1], 1u);
    } else {
      while (atomicAdd(&bar[2 * idx + 1], 0u) == 0u)
        __builtin_amdgcn_s_sleep(8);
    }
    __threadfence();  // acquire other blocks' writes
  }
  __syncthreads();
}

// ---------------------------------------------------------------------------
// Fused: [A] W-transpose (blocks 0..31) + qproj (2 rows/block)
//        [bar] [B] kvproj tile (row-tile b&255, col-tile b>>8)
//        [bar] [C] attn (samples 2b, 2b+1)
// ---------------------------------------------------------------------------
__global__ __launch_bounds__(256, 2) void fused_kernel(
    const float* __restrict__ enc, const float* __restrict__ soc,
    const int* __restrict__ starts, const int* __restrict__ ends,
    const float* __restrict__ Wq, const float* __restrict__ bq,
    const float* __restrict__ Wk, const float* __restrict__ bk,
    const float* __restrict__ Wv, const float* __restrict__ bv,
    unsigned short* __restrict__ kb, unsigned short* __restrict__ vb,
    unsigned short* __restrict__ WkT, unsigned short* __restrict__ WvT,
    float* __restrict__ qbuf, unsigned* bar, float* __restrict__ out) {
  __shared__ __align__(16) char LDS[49152];
  const int b = blockIdx.x;
  const int t = threadIdx.x;

  // ---------------- Phase A ----------------
  if (b < 32) {  // transpose one 64x64 tile of Wk or Wv -> bf16 W^T
    const float* W = (b & 16) ? Wv : Wk;
    unsigned short* WT = (b & 16) ? WvT : WkT;
    const int tile = b & 15;
    const int k0 = (tile >> 2) * 64, c0 = (tile & 3) * 64;
    const int tx = t & 63, ty = t >> 6;
    float(*ls)[65] = (float(*)[65])LDS;
#pragma unroll
    for (int kk = 0; kk < 16; ++kk)
      ls[tx][kk * 4 + ty] = W[(size_t)(k0 + kk * 4 + ty) * H + c0 + tx];
    __syncthreads();
#pragma unroll
    for (int cc = 0; cc < 16; ++cc) {
      const int c = cc * 4 + ty;
      WT[(size_t)(c0 + c) * H + k0 + tx] = f2bf(ls[c][tx]);
    }
    __syncthreads();  // LDS reused below
  }
  {  // qproj rows 2b, 2b+1
    const int row0 = b * 2;
    float(*xs)[H] = (float(*)[H])LDS;
    if (t < 128) {
      float4 v =
          *(const float4*)(enc + (size_t)(row0 + (t >> 6)) * H + (t & 63) * 4);
      *(float4*)(&xs[t >> 6][(t & 63) * 4]) = v;
    }
    __syncthreads();
    float acc0 = 0.f, acc1 = 0.f;
#pragma unroll 4
    for (int k = 0; k < H; ++k) {
      const float w = Wq[(size_t)k * H + t];
      acc0 = fmaf(xs[0][k], w, acc0);
      acc1 = fmaf(xs[1][k], w, acc1);
    }
    const float bias = bq[t];
    qbuf[(size_t)row0 * H + t] = fmaxf(acc0 + bias, 0.f) * 0.0625f;
    qbuf[(size_t)(row0 + 1) * H + t] = fmaxf(acc1 + bias, 0.f) * 0.0625f;
  }

  grid_barrier(bar, 0);

  // ---------------- Phase B: kvproj ----------------
  {
    unsigned short* As = (unsigned short*)LDS;
    unsigned short* Bks = As + 128 * 64;
    unsigned short* Bvs = Bks + 128 * 64;
    const int lane = t & 63, wid = t >> 6;
    const int brow = (b & 255) * 128;
    const int col0 = (b >> 8) * 128;

    const int srow = t >> 3;
    const int slin = t & 7;
    const int arow = t >> 1;
    const int sbase = (t & 1) * 4;

    f32x4 accK[4][4], accV[4][4];
#pragma unroll
    for (int m = 0; m < 4; ++m)
#pragma unroll
      for (int n = 0; n < 4; ++n) {
        accK[m][n] = (f32x4)0.f;
        accV[m][n] = (f32x4)0.f;
      }

    const int wr = wid >> 1, wc = wid & 1;

    for (int k0 = 0; k0 < H; k0 += 64) {
      float4 av[8];
      const float* arp = soc + (size_t)(brow + arow) * H + k0 + sbase * 8;
#pragma unroll
      for (int s = 0; s < 4; ++s) {
        av[2 * s] = *(const float4*)(arp + s * 8);
        av[2 * s + 1] = *(const float4*)(arp + s * 8 + 4);
      }
#pragma unroll
      for (int c = 0; c < 4; ++c) {
        const int row = c * 32 + srow;
        const int ssrc = slin ^ (row & 7);
        gload16(WkT + (size_t)(col0 + row) * H + k0 + ssrc * 8,
                (char*)Bks + c * 4096 + t * 16);
        gload16(WvT + (size_t)(col0 + row) * H + k0 + ssrc * 8,
                (char*)Bvs + c * 4096 + t * 16);
      }
#pragma unroll
      for (int s = 0; s < 4; ++s) {
        uint4 p;
        p.x = cvt_pk_bf16(av[2 * s].x, av[2 * s].y);
        p.y = cvt_pk_bf16(av[2 * s].z, av[2 * s].w);
        p.z = cvt_pk_bf16(av[2 * s + 1].x, av[2 * s + 1].y);
        p.w = cvt_pk_bf16(av[2 * s + 1].z, av[2 * s + 1].w);
        *(uint4*)((char*)As + arow * 128 + ((sbase + s) ^ (arow & 7)) * 16) = p;
      }
      asm volatile("s_waitcnt vmcnt(0)" ::: "memory");
      __syncthreads();
#pragma unroll
      for (int kk = 0; kk < 2; ++kk) {
        short8 af[4], bkf[4], bvf[4];
#pragma unroll
        for (int m = 0; m < 4; ++m) {
          const int ar = wr * 64 + m * 16 + (lane & 15);
          const int sl = (kk * 4 + (lane >> 4)) ^ (ar & 7);
          af[m] = *(const short8*)((const char*)As + ar * 128 + sl * 16);
        }
#pragma unroll
        for (int n = 0; n < 4; ++n) {
          const int br = wc * 64 + n * 16 + (lane & 15);
          const int sl = (kk * 4 + (lane >> 4)) ^ (br & 7);
          bkf[n] = *(const short8*)((const char*)Bks + br * 128 + sl * 16);
          bvf[n] = *(const short8*)((const char*)Bvs + br * 128 + sl * 16);
        }
#pragma unroll
        for (int m = 0; m < 4; ++m)
#pragma unroll
          for (int n = 0; n < 4; ++n) {
            accK[m][n] = __builtin_amdgcn_mfma_f32_16x16x32_bf16(
                af[m], bkf[n], accK[m][n], 0, 0, 0);
            accV[m][n] = __builtin_amdgcn_mfma_f32_16x16x32_bf16(
                af[m], bvf[n], accV[m][n], 0, 0, 0);
          }
      }
      __syncthreads();
    }

    float bkn[4], bvn[4];
#pragma unroll
    for (int n = 0; n < 4; ++n) {
      const int col = col0 + wc * 64 + n * 16 + (lane & 15);
      bkn[n] = bk[col];
      bvn[n] = bv[col];
    }
#pragma unroll
    for (int m = 0; m < 4; ++m)
#pragma unroll
      for (int n = 0; n < 4; ++n) {
        const int col = col0 + wc * 64 + n * 16 + (lane & 15);
#pragma unroll
        for (int r = 0; r < 4; ++r) {
          const int row = brow + wr * 64 + m * 16 + (lane >> 4) * 4 + r;
          kb[(size_t)row * H + col] = f2bf(fmaxf(accK[m][n][r] + bkn[n], 0.f));
          vb[(size_t)row * H + col] = f2bf(fmaxf(accV[m][n][r] + bvn[n], 0.f));
        }
      }
  }

  grid_barrier(bar, 1);

  // ---------------- Phase C: attn ----------------
  {
    float* sc = (float*)LDS;
    const int lane = t & 63, wave = t >> 6;
#pragma unroll 1
    for (int s = 0; s < 2; ++s) {
      const int row = b * 2 + s;
      const int start = starts[row];
      const int len = ends[row] - start;  // 1..64
      __syncthreads();                    // sc reuse across samples

      const int qp = (lane & 31) * 8;
      const float4 qv0 = *(const float4*)(qbuf + (size_t)row * H + qp);
      const float4 qv1 = *(const float4*)(qbuf + (size_t)row * H + qp + 4);

      for (int jj = wave * 2; jj < len; jj += 8) {
        const int j0 = jj + (lane >> 5);
        if (j0 < len) {
          const ushort8v k8 =
              *(const ushort8v*)(kb + (size_t)(start + j0) * H + qp);
          float sv = qv0.x * b2f(k8[0]) + qv0.y * b2f(k8[1]) +
                     qv0.z * b2f(k8[2]) + qv0.w * b2f(k8[3]) +
                     qv1.x * b2f(k8[4]) + qv1.y * b2f(k8[5]) +
                     qv1.z * b2f(k8[6]) + qv1.w * b2f(k8[7]);
#pragma unroll
          for (int off = 16; off; off >>= 1) sv += __shfl_xor(sv, off, 64);
          if ((lane & 31) == 0) sc[j0] = sv;
        }
      }
      __syncthreads();

      if (t < 64) {
        const float x = (t < len) ? sc[t] : -INFINITY;
        float m = x;
#pragma unroll
        for (int off = 32; off; off >>= 1) m = fmaxf(m, __shfl_xor(m, off, 64));
        const float p = (t < len) ? __expf(x - m) : 0.f;
        float ssum = p;
#pragma unroll
        for (int off = 32; off; off >>= 1) ssum += __shfl_xor(ssum, off, 64);
        sc[t] = p / ssum;
      }
      __syncthreads();

      const unsigned short* vp = vb + (size_t)start * H + t;
      float a0 = 0.f, a1 = 0.f, a2 = 0.f, a3 = 0.f;
      int j = 0;
      for (; j + 3 < len; j += 4) {
        a0 = fmaf(sc[j + 0], b2f(vp[(size_t)(j + 0) * H]), a0);
        a1 = fmaf(sc[j + 1], b2f(vp[(size_t)(j + 1) * H]), a1);
        a2 = fmaf(sc[j + 2], b2f(vp[(size_t)(j + 2) * H]), a2);
        a3 = fmaf(sc[j + 3], b2f(vp[(size_t)(j + 3) * H]), a3);
      }
      for (; j < len; ++j) a0 = fmaf(sc[j], b2f(vp[(size_t)j * H]), a0);
      out[(size_t)row * H + t] = (a0 + a1) + (a2 + a3);
    }
  }
}

// ---------------------------------------------------------------------------
extern "C" void kernel_launch(void* const* d_in, const int* in_sizes, int n_in,
                              void* d_out, int out_size, void* d_ws,
                              size_t ws_size, hipStream_t stream) {
  (void)in_sizes; (void)n_in; (void)out_size; (void)ws_size;
  const float* enc = (const float*)d_in[0];
  const float* soc = (const float*)d_in[1];
  const int* starts = (const int*)d_in[2];
  const int* ends = (const int*)d_in[3];
  const float* Wq = (const float*)d_in[4];
  const float* bq = (const float*)d_in[5];
  const float* Wk = (const float*)d_in[6];
  const float* bk = (const float*)d_in[7];
  const float* Wv = (const float*)d_in[8];
  const float* bv = (const float*)d_in[9];
  float* out = (float*)d_out;

  char* ws = (char*)d_ws;
  unsigned* bar = (unsigned*)ws;                          // 1 KB (uses 16 B)
  unsigned short* kb = (unsigned short*)(ws + 1024);      // 16 MB
  unsigned short* vb = kb + (size_t)NPOOL * H;            // 16 MB
  unsigned short* WkT = vb + (size_t)NPOOL * H;           // 128 KB
  unsigned short* WvT = WkT + H * H;                      // 128 KB
  float* qbuf = (float*)(WvT + H * H);                    // 1 MB

  hipMemsetAsync(bar, 0, 1024, stream);  // re-arm grid barrier every call
  fused_kernel<<<NB, 256, 0, stream>>>(enc, soc, starts, ends, Wq, bq, Wk, bk,
                                       Wv, bv, kb, vb, WkT, WvT, qbuf, bar,
                                       out);
}

// Round 6
// 60.731 us; speedup vs baseline: 2.6032x; 2.6032x over previous
//
#include <hip/hip_runtime.h>
#include <hip/hip_bf16.h>
#include <math.h>

#define H 256
#define BQ 1024
#define NPOOL 32768
#define MAXN 64

#define CONV_BLOCKS 4096   // NPOOL*H/(256*8)
#define TRANS_BLOCKS 32    // 2 matrices x 16 tiles of 64x64
#define QPROJ_BLOCKS 256   // BQ/4

typedef __attribute__((ext_vector_type(8))) short short8;
typedef __attribute__((ext_vector_type(8))) unsigned short ushort8v;
typedef __attribute__((ext_vector_type(4))) float f32x4;

__device__ __forceinline__ unsigned short f2bf(float f) {
  unsigned int u = __float_as_uint(f);
  unsigned int r = (u + 0x7fffu + ((u >> 16) & 1u)) >> 16;
  return (unsigned short)r;
}
__device__ __forceinline__ float b2f(unsigned short u) {
  return __uint_as_float((unsigned int)u << 16);
}
__device__ __forceinline__ void gload16(const void* g, void* l) {
  __builtin_amdgcn_global_load_lds(
      (const __attribute__((address_space(1))) unsigned int*)g,
      (__attribute__((address_space(3))) unsigned int*)l, 16, 0, 0);
}

// ---------------------------------------------------------------------------
// prep: [0,4096) convert soc->bf16 | [4096,4128) transpose Wk/Wv->bf16
//       | [4128,4384) qproj (4 rows/block, fp32)
// ---------------------------------------------------------------------------
__global__ __launch_bounds__(256) void prep_kernel(
    const float* __restrict__ soc, unsigned short* __restrict__ socb,
    const float* __restrict__ Wk, const float* __restrict__ Wv,
    unsigned short* __restrict__ WkT, unsigned short* __restrict__ WvT,
    const float* __restrict__ enc, const float* __restrict__ Wq,
    const float* __restrict__ bq, float* __restrict__ qbuf) {
  __shared__ float smem[64 * 65];
  const int b = blockIdx.x;
  const int t = threadIdx.x;

  if (b < CONV_BLOCKS) {
    const size_t i = ((size_t)b * 256 + t) * 8;
    const float4 a = *(const float4*)(soc + i);
    const float4 c = *(const float4*)(soc + i + 4);
    ushort8v r;
    r[0] = f2bf(a.x); r[1] = f2bf(a.y); r[2] = f2bf(a.z); r[3] = f2bf(a.w);
    r[4] = f2bf(c.x); r[5] = f2bf(c.y); r[6] = f2bf(c.z); r[7] = f2bf(c.w);
    *(ushort8v*)(socb + i) = r;
  } else if (b < CONV_BLOCKS + TRANS_BLOCKS) {
    const int bb = b - CONV_BLOCKS;
    const float* W = (bb & 16) ? Wv : Wk;
    unsigned short* WT = (bb & 16) ? WvT : WkT;
    const int tile = bb & 15;
    const int k0 = (tile >> 2) * 64, c0 = (tile & 3) * 64;
    const int tx = t & 63, ty = t >> 6;
    float (*ls)[65] = (float(*)[65])smem;
#pragma unroll
    for (int kk = 0; kk < 16; ++kk)
      ls[tx][kk * 4 + ty] = W[(size_t)(k0 + kk * 4 + ty) * H + c0 + tx];
    __syncthreads();
#pragma unroll
    for (int cc = 0; cc < 16; ++cc) {
      const int c = cc * 4 + ty;
      WT[(size_t)(c0 + c) * H + k0 + tx] = f2bf(ls[c][tx]);
    }
  } else {
    const int bb = b - CONV_BLOCKS - TRANS_BLOCKS;
    const int row0 = bb * 4;
    float (*xs)[H] = (float(*)[H])smem;
    {
      float4 v = *(const float4*)(enc + (size_t)(row0 + (t >> 6)) * H + (t & 63) * 4);
      *(float4*)(&xs[t >> 6][(t & 63) * 4]) = v;
    }
    __syncthreads();
    float acc[4] = {0.f, 0.f, 0.f, 0.f};
#pragma unroll 4
    for (int k = 0; k < H; ++k) {
      const float w = Wq[(size_t)k * H + t];
#pragma unroll
      for (int r = 0; r < 4; ++r) acc[r] = fmaf(xs[r][k], w, acc[r]);
    }
    const float bias = bq[t];
#pragma unroll
    for (int r = 0; r < 4; ++r)
      qbuf[(size_t)(row0 + r) * H + t] = fmaxf(acc[r] + bias, 0.f) * 0.0625f;
  }
}

// ---------------------------------------------------------------------------
// kvproj: K AND V per block (shared A tile). 128x128 tile, BK=64.
// TRUE double-buffered pipeline: 6 LDS buffers (A/Bk/Bv x 2), raw s_barrier
// + counted vmcnt(12) so next tile's loads stay in flight across barriers.
// grid = (NPOOL/128, 2 coltiles)
// ---------------------------------------------------------------------------
__global__ __launch_bounds__(256, 1) void kvproj_kernel(
    const unsigned short* __restrict__ socb,
    const unsigned short* __restrict__ WkT,
    const unsigned short* __restrict__ WvT,
    const float* __restrict__ bk, const float* __restrict__ bv,
    unsigned short* __restrict__ kout, unsigned short* __restrict__ vout) {
  // 2 pipeline halves x {A, Bk, Bv} x 16 KB = 96 KB
  __shared__ __align__(16) unsigned short LDSb[6 * 128 * 64];
  const int t = threadIdx.x;
  const int lane = t & 63, wid = t >> 6;
  const int brow = blockIdx.x * 128;
  const int col0 = blockIdx.y * 128;

  const int srow = t >> 3;   // 0..31 within a 32-row chunk
  const int slin = t & 7;    // 16B slot within row

  f32x4 accK[4][4], accV[4][4];
#pragma unroll
  for (int m = 0; m < 4; ++m)
#pragma unroll
    for (int n = 0; n < 4; ++n) { accK[m][n] = (f32x4)0.f; accV[m][n] = (f32x4)0.f; }

  const int wr = wid >> 1, wc = wid & 1;

  // stage K-tile kt into pipeline half pb: 12 x global_load_lds(16B)
#define STAGE(kt, pb)                                                       \
  {                                                                         \
    const int k0_ = (kt)*64;                                                \
    char* base_ = (char*)LDSb + (pb)*49152;                                 \
    _Pragma("unroll") for (int c = 0; c < 4; ++c) {                         \
      const int row_ = c * 32 + srow;                                       \
      const int ssrc_ = slin ^ (row_ & 7);                                  \
      gload16(socb + (size_t)(brow + row_) * H + k0_ + ssrc_ * 8,           \
              base_ + c * 4096 + t * 16);                                   \
      gload16(WkT + (size_t)(col0 + row_) * H + k0_ + ssrc_ * 8,            \
              base_ + 16384 + c * 4096 + t * 16);                           \
      gload16(WvT + (size_t)(col0 + row_) * H + k0_ + ssrc_ * 8,            \
              base_ + 32768 + c * 4096 + t * 16);                           \
    }                                                                       \
  }

  STAGE(0, 0);
#pragma unroll
  for (int kt = 0; kt < 4; ++kt) {
    if (kt < 3) {
      STAGE(kt + 1, (kt + 1) & 1);
      asm volatile("s_waitcnt vmcnt(12)" ::: "memory");  // tile kt arrived
    } else {
      asm volatile("s_waitcnt vmcnt(0)" ::: "memory");
    }
    __builtin_amdgcn_s_barrier();  // raw: no implicit vmcnt(0) drain
    const char* Ab = (const char*)LDSb + (kt & 1) * 49152;
    const char* Bkb = Ab + 16384;
    const char* Bvb = Ab + 32768;
#pragma unroll
    for (int kk = 0; kk < 2; ++kk) {
      short8 af[4], bkf[4], bvf[4];
#pragma unroll
      for (int m = 0; m < 4; ++m) {
        const int ar = wr * 64 + m * 16 + (lane & 15);
        const int sl = (kk * 4 + (lane >> 4)) ^ (ar & 7);
        af[m] = *(const short8*)(Ab + ar * 128 + sl * 16);
      }
#pragma unroll
      for (int n = 0; n < 4; ++n) {
        const int br = wc * 64 + n * 16 + (lane & 15);
        const int sl = (kk * 4 + (lane >> 4)) ^ (br & 7);
        bkf[n] = *(const short8*)(Bkb + br * 128 + sl * 16);
        bvf[n] = *(const short8*)(Bvb + br * 128 + sl * 16);
      }
#pragma unroll
      for (int m = 0; m < 4; ++m)
#pragma unroll
        for (int n = 0; n < 4; ++n) {
          accK[m][n] = __builtin_amdgcn_mfma_f32_16x16x32_bf16(
              af[m], bkf[n], accK[m][n], 0, 0, 0);
          accV[m][n] = __builtin_amdgcn_mfma_f32_16x16x32_bf16(
              af[m], bvf[n], accV[m][n], 0, 0, 0);
        }
    }
    __builtin_amdgcn_s_barrier();  // all waves done reading this half
  }
#undef STAGE

  float bkn[4], bvn[4];
#pragma unroll
  for (int n = 0; n < 4; ++n) {
    const int col = col0 + wc * 64 + n * 16 + (lane & 15);
    bkn[n] = bk[col]; bvn[n] = bv[col];
  }
#pragma unroll
  for (int m = 0; m < 4; ++m)
#pragma unroll
    for (int n = 0; n < 4; ++n) {
      const int col = col0 + wc * 64 + n * 16 + (lane & 15);
#pragma unroll
      for (int r = 0; r < 4; ++r) {
        const int row = brow + wr * 64 + m * 16 + (lane >> 4) * 4 + r;
        kout[(size_t)row * H + col] = f2bf(fmaxf(accK[m][n][r] + bkn[n], 0.f));
        vout[(size_t)row * H + col] = f2bf(fmaxf(accV[m][n][r] + bvn[n], 0.f));
      }
    }
}

// ---------------------------------------------------------------------------
// attn: per-sample sliced attention; q fp32, k/v bf16 (r4 version, unchanged)
// ---------------------------------------------------------------------------
__global__ __launch_bounds__(256) void attn_kernel(
    const float* __restrict__ qb, const unsigned short* __restrict__ kb,
    const unsigned short* __restrict__ vb, const int* __restrict__ starts,
    const int* __restrict__ ends, float* __restrict__ out) {
  __shared__ float sc[MAXN];
  const int row = blockIdx.x, t = threadIdx.x;
  const int lane = t & 63, wave = t >> 6;
  const int start = starts[row];
  const int len = ends[row] - start;  // 1..64

  const int qp = (lane & 31) * 8;
  const float4 qv0 = *(const float4*)(qb + (size_t)row * H + qp);
  const float4 qv1 = *(const float4*)(qb + (size_t)row * H + qp + 4);

  for (int jj = wave * 2; jj < len; jj += 8) {
    const int j0 = jj + (lane >> 5);
    if (j0 < len) {
      const ushort8v k8 =
          *(const ushort8v*)(kb + (size_t)(start + j0) * H + qp);
      float s = qv0.x * b2f(k8[0]) + qv0.y * b2f(k8[1]) +
                qv0.z * b2f(k8[2]) + qv0.w * b2f(k8[3]) +
                qv1.x * b2f(k8[4]) + qv1.y * b2f(k8[5]) +
                qv1.z * b2f(k8[6]) + qv1.w * b2f(k8[7]);
#pragma unroll
      for (int off = 16; off; off >>= 1) s += __shfl_xor(s, off, 64);
      if ((lane & 31) == 0) sc[j0] = s;
    }
  }
  __syncthreads();

  if (t < 64) {
    const float x = (t < len) ? sc[t] : -INFINITY;
    float m = x;
#pragma unroll
    for (int off = 32; off; off >>= 1) m = fmaxf(m, __shfl_xor(m, off, 64));
    const float p = (t < len) ? __expf(x - m) : 0.f;
    float ssum = p;
#pragma unroll
    for (int off = 32; off; off >>= 1) ssum += __shfl_xor(ssum, off, 64);
    sc[t] = p / ssum;
  }
  __syncthreads();

  const unsigned short* vp = vb + (size_t)start * H + t;
  float a0 = 0.f, a1 = 0.f, a2 = 0.f, a3 = 0.f;
  int j = 0;
  for (; j + 3 < len; j += 4) {
    a0 = fmaf(sc[j + 0], b2f(vp[(size_t)(j + 0) * H]), a0);
    a1 = fmaf(sc[j + 1], b2f(vp[(size_t)(j + 1) * H]), a1);
    a2 = fmaf(sc[j + 2], b2f(vp[(size_t)(j + 2) * H]), a2);
    a3 = fmaf(sc[j + 3], b2f(vp[(size_t)(j + 3) * H]), a3);
  }
  for (; j < len; ++j) a0 = fmaf(sc[j], b2f(vp[(size_t)j * H]), a0);
  out[(size_t)row * H + t] = (a0 + a1) + (a2 + a3);
}

// ---------------------------------------------------------------------------
extern "C" void kernel_launch(void* const* d_in, const int* in_sizes, int n_in,
                              void* d_out, int out_size, void* d_ws,
                              size_t ws_size, hipStream_t stream) {
  (void)in_sizes; (void)n_in; (void)out_size; (void)ws_size;
  const float* enc = (const float*)d_in[0];
  const float* soc = (const float*)d_in[1];
  const int* starts = (const int*)d_in[2];
  const int* ends = (const int*)d_in[3];
  const float* Wq = (const float*)d_in[4];
  const float* bq = (const float*)d_in[5];
  const float* Wk = (const float*)d_in[6];
  const float* bk = (const float*)d_in[7];
  const float* Wv = (const float*)d_in[8];
  const float* bv = (const float*)d_in[9];
  float* out = (float*)d_out;

  unsigned short* kb = (unsigned short*)d_ws;            // 16 MB
  unsigned short* vb = kb + (size_t)NPOOL * H;           // 16 MB
  unsigned short* socb = vb + (size_t)NPOOL * H;         // 16 MB
  unsigned short* WkT = socb + (size_t)NPOOL * H;        // 128 KB
  unsigned short* WvT = WkT + H * H;                     // 128 KB
  float* qbuf = (float*)(WvT + H * H);                   // 1 MB

  prep_kernel<<<CONV_BLOCKS + TRANS_BLOCKS + QPROJ_BLOCKS, 256, 0, stream>>>(
      soc, socb, Wk, Wv, WkT, WvT, enc, Wq, bq, qbuf);
  kvproj_kernel<<<dim3(NPOOL / 128, 2), 256, 0, stream>>>(
      socb, WkT, WvT, bk, bv, kb, vb);
  attn_kernel<<<BQ, 256, 0, stream>>>(qbuf, kb, vb, starts, ends, out);
}